// Round 1
// baseline (5609.525 us; speedup 1.0000x reference)
//
#include <hip/hip_runtime.h>

#define DI __device__ __forceinline__

constexpr int BB   = 128;   // batch
constexpr int TT   = 512;   // seq len
constexpr int HH   = 768;   // hidden
constexpr int G3   = 3 * HH;   // 2304
constexpr int VOC  = 128;

// recurrence partitioning
constexpr int NU   = 48;    // unit-blocks per batch group
constexpr int UB   = 16;    // hidden units per unit-block
constexpr int NGRP = 2;     // batch groups
constexpr int BGRP = 64;    // rows per group
constexpr int KC   = 24;    // k-chunks of 32 (768 = 24*32)

// workspace offsets (bytes); total need ~5.51 MB
constexpr size_t OFF_GE    = 0;                       // [VOC][G3] f32  = 1,179,648
constexpr size_t OFF_WIMG  = 1179648;                 // [NU][3][KC][64][8] f16 = 3,538,944
constexpr size_t OFF_H16   = OFF_WIMG + 3538944;      // [2][BB][HH] f16 = 393,216
constexpr size_t OFF_H32   = OFF_H16 + 393216;        // [BB][HH] f32   = 393,216
constexpr size_t OFF_FLAGS = OFF_H32 + 393216;        // [NGRP][NU] int

constexpr int LDS_BYTES = 90112;  // 73,728 used; padded >80KB to force 1 block/CU

typedef _Float16 f16x8 __attribute__((ext_vector_type(8)));
typedef float    f32x4 __attribute__((ext_vector_type(4)));

DI float sigm(float x) { return __builtin_amdgcn_rcpf(1.0f + __expf(-x)); }
DI float tanh_fast(float x) {
  float e = __expf(-2.0f * fabsf(x));
  float r = (1.0f - e) * __builtin_amdgcn_rcpf(1.0f + e);
  return copysignf(r, x);
}

// ---------------- K0: zero h16 double-buffer + flags ----------------
__global__ void k_zero(uint4* h16q, int n16, int* flags, int nflags) {
  int i = blockIdx.x * 256 + threadIdx.x;
  uint4 z; z.x = 0; z.y = 0; z.z = 0; z.w = 0;
  if (i < n16) h16q[i] = z;
  if (i < nflags) flags[i] = 0;
}

// ---------------- K1: W_hh -> fp16 MFMA B-fragment image ----------------
// image index: ((j*3 + nt)*KC + kc)*64 + lane, 8 halfs each.
// B[k][n]: n = lane&15 (unit col within tile), k = kc*32 + (lane>>4)*8 + q
// value = W_hh[g][k], g = nt*768 + j*16 + (lane&15)
__global__ void k_prep_w(const float* __restrict__ Whh, _Float16* __restrict__ wimg) {
  int tid = blockIdx.x * 256 + threadIdx.x;       // 48*3*24*64 = 221,184 total
  if (tid >= NU * 3 * KC * 64) return;
  int l  = tid & 63;
  int fi = tid >> 6;
  int kc = fi % KC;
  int nt = (fi / KC) % 3;
  int j  = fi / (KC * 3);
  int g  = nt * HH + j * UB + (l & 15);
  int k0 = kc * 32 + (l >> 4) * 8;
  const float* src = Whh + (size_t)g * HH + k0;
  f16x8 o;
#pragma unroll
  for (int q = 0; q < 8; ++q) o[q] = (_Float16)src[q];
  ((f16x8*)wimg)[tid] = o;
}

// ---------------- K2: ge[v][g] = emb[v,:] . W_ih[g,:] + b_ih[g] ----------------
// grid (G3/256=9, VOC/16=8), block 256. Thread: one g, 16 v's.
__global__ void k_prep_ge(const float* __restrict__ emb, const float* __restrict__ Wih,
                          const float* __restrict__ bih, float* __restrict__ ge) {
  int g  = blockIdx.x * 256 + threadIdx.x;
  int v0 = blockIdx.y * 16;
  float acc[16];
  float b = bih[g];
#pragma unroll
  for (int i = 0; i < 16; ++i) acc[i] = b;
  const float* wrow = Wih + (size_t)g * HH;
  for (int e = 0; e < HH; e += 4) {
    float4 w = *(const float4*)(wrow + e);
#pragma unroll
    for (int i = 0; i < 16; ++i) {
      float4 m = *(const float4*)(emb + (size_t)(v0 + i) * HH + e);  // uniform -> L1 broadcast
      acc[i] = fmaf(w.x, m.x, acc[i]);
      acc[i] = fmaf(w.y, m.y, acc[i]);
      acc[i] = fmaf(w.z, m.z, acc[i]);
      acc[i] = fmaf(w.w, m.w, acc[i]);
    }
  }
#pragma unroll
  for (int i = 0; i < 16; ++i) ge[(size_t)(v0 + i) * G3 + g] = acc[i];
}

// ---------------- K3: persistent GRU recurrence ----------------
// 96 blocks x 256 thr. block -> (grp = bid/NU, j = bid%NU). Wave w = m-tile (16 rows).
__global__ __launch_bounds__(256, 1) void k_gru(
    const int* __restrict__ x,       // [BB][TT]
    const float* __restrict__ ge,    // [VOC][G3]
    const float* __restrict__ bhh,   // [G3]
    const _Float16* __restrict__ wimg,
    _Float16* h16,                   // [2][BB][HH]
    float* __restrict__ h32,         // [BB][HH]
    int* flags)                      // [NGRP][NU]
{
  extern __shared__ char smem[];
  _Float16* lds = (_Float16*)smem;

  const int tid  = threadIdx.x;
  const int lane = tid & 63;
  const int wid  = tid >> 6;
  const int bid  = blockIdx.x;
  const int grp  = bid / NU;
  const int j    = bid % NU;
  const int b0   = grp * BGRP;
  const int u0   = j * UB;
  int* gflags = flags + grp * NU;

  // stage this block's W fragments into LDS (73,728 B)
  {
    const uint4* src = (const uint4*)(wimg + (size_t)j * (3 * KC * 64 * 8));
    uint4* dst = (uint4*)lds;
#pragma unroll
    for (int r = 0; r < 18; ++r) dst[tid + 256 * r] = src[tid + 256 * r];
  }

  const int col  = lane & 15;   // D col / A row / B col within tile
  const int krow = lane >> 4;   // k sub-chunk selector
  const int bm   = b0 + wid * 16;

  const float bh_r = bhh[0 * HH + u0 + col];
  const float bh_z = bhh[1 * HH + u0 + col];
  const float bh_n = bhh[2 * HH + u0 + col];

  float hprev[4] = {0.f, 0.f, 0.f, 0.f};

  _Float16* hb0 = h16;
  _Float16* hb1 = h16 + (size_t)BB * HH;

  __syncthreads();

  for (int t = 0; t < TT; ++t) {
    // ---- gather x and ge for this step (independent of h; overlaps the spin) ----
    int xv[4];
#pragma unroll
    for (int q = 0; q < 4; ++q) xv[q] = x[(size_t)(bm + krow * 4 + q) * TT + t];
    float ger[4], gez[4], gen[4];
#pragma unroll
    for (int q = 0; q < 4; ++q) {
      const float* gp = ge + (size_t)xv[q] * G3 + u0 + col;
      ger[q] = gp[0 * HH];
      gez[q] = gp[1 * HH];
      gen[q] = gp[2 * HH];
    }

    // ---- wait for h(t) from all unit-blocks of this batch group ----
    if (t > 0) {
      const bool act = lane < NU;
      for (;;) {
        int f = act ? __hip_atomic_load(&gflags[lane], __ATOMIC_RELAXED,
                                        __HIP_MEMORY_SCOPE_AGENT)
                    : t;
        if (__all(f >= t)) break;
        __builtin_amdgcn_s_sleep(1);
      }
      __builtin_amdgcn_fence(__ATOMIC_ACQUIRE, "agent");
    }

    // ---- gh = h . W^T for this slice: 3 n-tiles (r,z,n gates) x 24 k-chunks ----
    f32x4 acc0 = {bh_r, bh_r, bh_r, bh_r};
    f32x4 acc1 = {bh_z, bh_z, bh_z, bh_z};
    f32x4 acc2 = {bh_n, bh_n, bh_n, bh_n};
    const _Float16* hb = (t & 1) ? hb1 : hb0;
    const _Float16* arow = hb + (size_t)(bm + col) * HH + krow * 8;
    const f16x8* bfr = (const f16x8*)lds;
#pragma unroll
    for (int kc = 0; kc < KC; ++kc) {
      f16x8 a = *(const f16x8*)(arow + kc * 32);
      acc0 = __builtin_amdgcn_mfma_f32_16x16x32_f16(a, bfr[(0 * KC + kc) * 64 + lane], acc0, 0, 0, 0);
      acc1 = __builtin_amdgcn_mfma_f32_16x16x32_f16(a, bfr[(1 * KC + kc) * 64 + lane], acc1, 0, 0, 0);
      acc2 = __builtin_amdgcn_mfma_f32_16x16x32_f16(a, bfr[(2 * KC + kc) * 64 + lane], acc2, 0, 0, 0);
    }

    // ---- gates + state update (fp32), write fp16 h for exchange ----
    _Float16* hn = (t & 1) ? hb0 : hb1;
#pragma unroll
    for (int q = 0; q < 4; ++q) {
      float r = sigm(acc0[q] + ger[q]);
      float z = sigm(acc1[q] + gez[q]);
      float n = tanh_fast(gen[q] + r * acc2[q]);
      float h = n + z * (hprev[q] - n);
      hprev[q] = h;
      int brow = bm + krow * 4 + q;
      if (t == TT - 1) {
        h32[(size_t)brow * HH + u0 + col] = h;
      } else {
        hn[(size_t)brow * HH + u0 + col] = (_Float16)h;
      }
    }

    if (t < TT - 1) {
      __syncthreads();  // all waves' stores issued & waited before release
      if (tid == 0)
        __hip_atomic_store(&gflags[j], t + 1, __ATOMIC_RELEASE, __HIP_MEMORY_SCOPE_AGENT);
    }
  }
}

// ---------------- K4: out = h32 @ fc_W^T + fc_b ----------------
__global__ void k_fc(const float* __restrict__ h32, const float* __restrict__ fcW,
                     const float* __restrict__ fcb, float* __restrict__ out) {
  int o  = blockIdx.x * 256 + threadIdx.x;   // 768
  int b0 = blockIdx.y * 16;                  // 128
  float acc[16];
  float bi = fcb[o];
#pragma unroll
  for (int i = 0; i < 16; ++i) acc[i] = bi;
  const float* wrow = fcW + (size_t)o * HH;
  for (int e = 0; e < HH; e += 4) {
    float4 w = *(const float4*)(wrow + e);
#pragma unroll
    for (int i = 0; i < 16; ++i) {
      float4 m = *(const float4*)(h32 + (size_t)(b0 + i) * HH + e);
      acc[i] = fmaf(w.x, m.x, acc[i]);
      acc[i] = fmaf(w.y, m.y, acc[i]);
      acc[i] = fmaf(w.z, m.z, acc[i]);
      acc[i] = fmaf(w.w, m.w, acc[i]);
    }
  }
#pragma unroll
  for (int i = 0; i < 16; ++i) out[(size_t)(b0 + i) * HH + o] = acc[i];
}

extern "C" void kernel_launch(void* const* d_in, const int* in_sizes, int n_in,
                              void* d_out, int out_size, void* d_ws, size_t ws_size,
                              hipStream_t stream) {
  const int*   x   = (const int*)d_in[0];
  const float* emb = (const float*)d_in[1];
  const float* Wih = (const float*)d_in[2];
  const float* Whh = (const float*)d_in[3];
  const float* bih = (const float*)d_in[4];
  const float* bhh = (const float*)d_in[5];
  const float* fcW = (const float*)d_in[6];
  const float* fcb = (const float*)d_in[7];
  float* out = (float*)d_out;

  char* ws = (char*)d_ws;
  float*     ge    = (float*)(ws + OFF_GE);
  _Float16*  wimg  = (_Float16*)(ws + OFF_WIMG);
  _Float16*  h16   = (_Float16*)(ws + OFF_H16);
  float*     h32   = (float*)(ws + OFF_H32);
  int*       flags = (int*)(ws + OFF_FLAGS);

  // zero h16 double buffer (2*128*768 halfs = 393,216 B = 24,576 uint4) + 96 flags
  k_zero<<<96, 256, 0, stream>>>((uint4*)h16, 24576, flags, NGRP * NU);
  k_prep_w<<<864, 256, 0, stream>>>(Whh, wimg);
  k_prep_ge<<<dim3(9, 8), 256, 0, stream>>>(emb, Wih, bih, ge);

  hipFuncSetAttribute(reinterpret_cast<const void*>(k_gru),
                      hipFuncAttributeMaxDynamicSharedMemorySize, LDS_BYTES);
  k_gru<<<NGRP * NU, 256, LDS_BYTES, stream>>>(x, ge, bhh, wimg, h16, h32, flags);

  k_fc<<<dim3(3, 8), 256, 0, stream>>>(h32, fcW, fcb, out);
}

// Round 2
// 2740.256 us; speedup vs baseline: 2.0471x; 2.0471x over previous
//
#include <hip/hip_runtime.h>

#define DI __device__ __forceinline__

constexpr int BB   = 128;   // batch
constexpr int TT   = 512;   // seq len
constexpr int HH   = 768;   // hidden
constexpr int G3   = 3 * HH;   // 2304
constexpr int VOC  = 128;

// recurrence partitioning
constexpr int NU   = 48;    // unit-blocks per batch group (16 units each)
constexpr int UB   = 16;    // hidden units per unit-block
constexpr int NGRP = 4;     // batch groups
constexpr int BGRP = 32;    // rows per group
constexpr int KC   = 24;    // k-chunks of 32 (768 = 24*32)

// workspace offsets (bytes)
constexpr size_t OFF_GE    = 0;                       // [VOC][G3] f32  = 1,179,648
constexpr size_t OFF_WIMG  = 1179648;                 // [NU][3][KC][64][8] f16 = 3,538,944
constexpr size_t OFF_H16   = OFF_WIMG + 3538944;      // [2][BB][HH] f16 = 393,216
constexpr size_t OFF_H32   = OFF_H16 + 393216;        // [BB][HH] f32   = 393,216
constexpr size_t OFF_FLAGS = OFF_H32 + 393216;        // [NGRP][NU] int = 768

constexpr int LDS_W_BYTES = 73728;                 // weight fragments
constexpr int LDS_BYTES   = 90112;                 // pad >80KB -> 1 block/CU

typedef _Float16 f16x8 __attribute__((ext_vector_type(8)));
typedef float    f32x4 __attribute__((ext_vector_type(4)));

DI float sigm(float x) { return __builtin_amdgcn_rcpf(1.0f + __expf(-x)); }
DI float tanh_fast(float x) {
  float e = __expf(-2.0f * fabsf(x));
  float r = (1.0f - e) * __builtin_amdgcn_rcpf(1.0f + e);
  return copysignf(r, x);
}

// L2-bypassing (device-coherent, lands/reads at L3) memory ops
DI f16x8 load_l3_x4(const void* p) {
  f16x8 r;
  asm volatile("global_load_dwordx4 %0, %1, off sc0 sc1"
               : "=v"(r) : "v"(p) : "memory");
  return r;
}
DI void store_l3_x2(void* p, uint2 v) {
  asm volatile("global_store_dwordx2 %0, %1, off sc0 sc1"
               :: "v"(p), "v"(v) : "memory");
}
DI void wait_vm0() { asm volatile("s_waitcnt vmcnt(0)" ::: "memory"); }
DI void wait_lgkm0() { asm volatile("s_waitcnt lgkmcnt(0)" ::: "memory"); }

// ---------------- K0: zero h16 double-buffer + flags ----------------
__global__ void k_zero(uint4* h16q, int n16, int* flags, int nflags) {
  int i = blockIdx.x * 256 + threadIdx.x;
  uint4 z; z.x = 0; z.y = 0; z.z = 0; z.w = 0;
  if (i < n16) h16q[i] = z;
  if (i < nflags) flags[i] = 0;
}

// ---------------- K1: W_hh -> fp16 MFMA B-fragment image ----------------
// image index: ((j*3 + nt)*KC + kc)*64 + lane, 8 halfs each.
// B[k][n]: n = lane&15 (unit col within tile), k = kc*32 + (lane>>4)*8 + q
// value = W_hh[g][k], g = nt*768 + j*16 + (lane&15)
__global__ void k_prep_w(const float* __restrict__ Whh, _Float16* __restrict__ wimg) {
  int tid = blockIdx.x * 256 + threadIdx.x;       // 48*3*24*64 = 221,184 total
  if (tid >= NU * 3 * KC * 64) return;
  int l  = tid & 63;
  int fi = tid >> 6;
  int kc = fi % KC;
  int nt = (fi / KC) % 3;
  int j  = fi / (KC * 3);
  int g  = nt * HH + j * UB + (l & 15);
  int k0 = kc * 32 + (l >> 4) * 8;
  const float* src = Whh + (size_t)g * HH + k0;
  f16x8 o;
#pragma unroll
  for (int q = 0; q < 8; ++q) o[q] = (_Float16)src[q];
  ((f16x8*)wimg)[tid] = o;
}

// ---------------- K2: ge[v][g] = emb[v,:] . W_ih[g,:] + b_ih[g] ----------------
__global__ void k_prep_ge(const float* __restrict__ emb, const float* __restrict__ Wih,
                          const float* __restrict__ bih, float* __restrict__ ge) {
  int g  = blockIdx.x * 256 + threadIdx.x;
  int v0 = blockIdx.y * 16;
  float acc[16];
  float b = bih[g];
#pragma unroll
  for (int i = 0; i < 16; ++i) acc[i] = b;
  const float* wrow = Wih + (size_t)g * HH;
  for (int e = 0; e < HH; e += 4) {
    float4 w = *(const float4*)(wrow + e);
#pragma unroll
    for (int i = 0; i < 16; ++i) {
      float4 m = *(const float4*)(emb + (size_t)(v0 + i) * HH + e);
      acc[i] = fmaf(w.x, m.x, acc[i]);
      acc[i] = fmaf(w.y, m.y, acc[i]);
      acc[i] = fmaf(w.z, m.z, acc[i]);
      acc[i] = fmaf(w.w, m.w, acc[i]);
    }
  }
#pragma unroll
  for (int i = 0; i < 16; ++i) ge[(size_t)(v0 + i) * G3 + g] = acc[i];
}

// ---------------- K3: persistent GRU recurrence ----------------
// 192 blocks x 128 thr. block -> (grp = bid/NU, j = bid%NU). Wave wid = m-tile (16 rows).
__global__ __launch_bounds__(128, 1) void k_gru(
    const int* __restrict__ x,       // [BB][TT]
    const float* __restrict__ ge,    // [VOC][G3]
    const float* __restrict__ bhh,   // [G3]
    const _Float16* __restrict__ wimg,
    _Float16* h16,                   // [2][BB][HH]
    float* __restrict__ h32,         // [BB][HH]
    int* flags)                      // [NGRP][NU]
{
  extern __shared__ char smem[];
  _Float16* lds = (_Float16*)smem;                       // weight frags (73,728 B)
  _Float16* st  = (_Float16*)(smem + LDS_W_BYTES);       // pack staging (1 KB)

  const int tid  = threadIdx.x;
  const int lane = tid & 63;
  const int wid  = tid >> 6;
  const int bid  = blockIdx.x;
  const int grp  = bid / NU;
  const int j    = bid % NU;
  const int b0   = grp * BGRP;
  const int u0   = j * UB;
  int* gflags = flags + grp * NU;

  // stage this block's W fragments into LDS (73,728 B = 4608 uint4 / 128 thr = 36)
  {
    const uint4* src = (const uint4*)(wimg + (size_t)j * (3 * KC * 64 * 8));
    uint4* dst = (uint4*)lds;
#pragma unroll
    for (int r = 0; r < 36; ++r) dst[tid + 128 * r] = src[tid + 128 * r];
  }

  const int col  = lane & 15;   // D col / A row / B col within tile
  const int krow = lane >> 4;   // k sub-chunk selector
  const int bm   = b0 + wid * 16;

  const float bh_r = bhh[0 * HH + u0 + col];
  const float bh_z = bhh[1 * HH + u0 + col];
  const float bh_n = bhh[2 * HH + u0 + col];

  float hprev[4] = {0.f, 0.f, 0.f, 0.f};

  _Float16* hb0 = h16;
  _Float16* hb1 = h16 + (size_t)BB * HH;

  __syncthreads();

  for (int t = 0; t < TT; ++t) {
    // ---- gather x and ge for this step (independent of h; overlaps the spin) ----
    int xv[4];
#pragma unroll
    for (int q = 0; q < 4; ++q) xv[q] = x[(size_t)(bm + krow * 4 + q) * TT + t];
    float ger[4], gez[4], gen[4];
#pragma unroll
    for (int q = 0; q < 4; ++q) {
      const float* gp = ge + (size_t)xv[q] * G3 + u0 + col;
      ger[q] = gp[0 * HH];
      gez[q] = gp[1 * HH];
      gen[q] = gp[2 * HH];
    }

    // ---- wait for h(t) from all unit-blocks of this batch group ----
    if (t > 0) {
      const bool act = lane < NU;
      for (;;) {
        int f = act ? __hip_atomic_load(&gflags[lane], __ATOMIC_RELAXED,
                                        __HIP_MEMORY_SCOPE_AGENT)
                    : t;
        if (__all(f >= t)) break;
        __builtin_amdgcn_s_sleep(1);
      }
    }
    asm volatile("" ::: "memory");  // keep A-loads below the spin

    // ---- A fragments: 24 x 16B L2-bypassing loads straight to registers ----
    const _Float16* hb = (t & 1) ? hb1 : hb0;
    const char* abase = (const char*)(hb + (size_t)(bm + col) * HH + krow * 8);
    f16x8 a[KC];
#pragma unroll
    for (int kc = 0; kc < KC; ++kc) a[kc] = load_l3_x4(abase + kc * 64);
    wait_vm0();
    __builtin_amdgcn_sched_barrier(0);  // MFMAs must not hoist above the wait

    // ---- gh = h . W^T : 3 gates x 24 k-chunks ----
    f32x4 acc0 = {bh_r, bh_r, bh_r, bh_r};
    f32x4 acc1 = {bh_z, bh_z, bh_z, bh_z};
    f32x4 acc2 = {bh_n, bh_n, bh_n, bh_n};
    const f16x8* bfr = (const f16x8*)lds;
#pragma unroll
    for (int kc = 0; kc < KC; ++kc) {
      acc0 = __builtin_amdgcn_mfma_f32_16x16x32_f16(a[kc], bfr[(0 * KC + kc) * 64 + lane], acc0, 0, 0, 0);
      acc1 = __builtin_amdgcn_mfma_f32_16x16x32_f16(a[kc], bfr[(1 * KC + kc) * 64 + lane], acc1, 0, 0, 0);
      acc2 = __builtin_amdgcn_mfma_f32_16x16x32_f16(a[kc], bfr[(2 * KC + kc) * 64 + lane], acc2, 0, 0, 0);
    }

    // ---- gates + state update (fp32) ----
    float hv[4];
#pragma unroll
    for (int q = 0; q < 4; ++q) {
      float r = sigm(acc0[q] + ger[q]);
      float z = sigm(acc1[q] + gez[q]);
      float n = tanh_fast(gen[q] + r * acc2[q]);
      float h = n + z * (hprev[q] - n);
      hprev[q] = h;
      hv[q] = h;
    }

    if (t == TT - 1) {
#pragma unroll
      for (int q = 0; q < 4; ++q)
        h32[(size_t)(bm + krow * 4 + q) * HH + u0 + col] = hv[q];
    } else {
      // ---- pack 16x16 f16 slice via LDS (in-wave transpose), bypass-store 8B/lane ----
#pragma unroll
      for (int q = 0; q < 4; ++q)
        st[wid * 256 + (krow * 4 + q) * 16 + col] = (_Float16)hv[q];
      wait_lgkm0();
      __builtin_amdgcn_sched_barrier(0);
      int rr = lane >> 2;       // row within m-tile
      int qq = lane & 3;        // 4-unit quarter
      uint2 v = *(const uint2*)&st[wid * 256 + rr * 16 + qq * 4];
      _Float16* hn = (t & 1) ? hb0 : hb1;
      store_l3_x2((char*)(hn + (size_t)(bm + rr) * HH + u0 + qq * 4), v);
      wait_vm0();               // stores acked at L3 before flag
      __syncthreads();          // both waves done
      if (tid == 0)
        __hip_atomic_store(&gflags[j], t + 1, __ATOMIC_RELAXED,
                           __HIP_MEMORY_SCOPE_AGENT);
    }
  }
}

// ---------------- K4: out = h32 @ fc_W^T + fc_b ----------------
__global__ void k_fc(const float* __restrict__ h32, const float* __restrict__ fcW,
                     const float* __restrict__ fcb, float* __restrict__ out) {
  int o  = blockIdx.x * 256 + threadIdx.x;   // 768
  int b0 = blockIdx.y * 16;                  // 128
  float acc[16];
  float bi = fcb[o];
#pragma unroll
  for (int i = 0; i < 16; ++i) acc[i] = bi;
  const float* wrow = fcW + (size_t)o * HH;
  for (int e = 0; e < HH; e += 4) {
    float4 w = *(const float4*)(wrow + e);
#pragma unroll
    for (int i = 0; i < 16; ++i) {
      float4 m = *(const float4*)(h32 + (size_t)(b0 + i) * HH + e);
      acc[i] = fmaf(w.x, m.x, acc[i]);
      acc[i] = fmaf(w.y, m.y, acc[i]);
      acc[i] = fmaf(w.z, m.z, acc[i]);
      acc[i] = fmaf(w.w, m.w, acc[i]);
    }
  }
#pragma unroll
  for (int i = 0; i < 16; ++i) out[(size_t)(b0 + i) * HH + o] = acc[i];
}

extern "C" void kernel_launch(void* const* d_in, const int* in_sizes, int n_in,
                              void* d_out, int out_size, void* d_ws, size_t ws_size,
                              hipStream_t stream) {
  const int*   x   = (const int*)d_in[0];
  const float* emb = (const float*)d_in[1];
  const float* Wih = (const float*)d_in[2];
  const float* Whh = (const float*)d_in[3];
  const float* bih = (const float*)d_in[4];
  const float* bhh = (const float*)d_in[5];
  const float* fcW = (const float*)d_in[6];
  const float* fcb = (const float*)d_in[7];
  float* out = (float*)d_out;

  char* ws = (char*)d_ws;
  float*     ge    = (float*)(ws + OFF_GE);
  _Float16*  wimg  = (_Float16*)(ws + OFF_WIMG);
  _Float16*  h16   = (_Float16*)(ws + OFF_H16);
  float*     h32   = (float*)(ws + OFF_H32);
  int*       flags = (int*)(ws + OFF_FLAGS);

  // zero h16 double buffer (393,216 B = 24,576 uint4) + 192 flags
  k_zero<<<96, 256, 0, stream>>>((uint4*)h16, 24576, flags, NGRP * NU);
  k_prep_w<<<864, 256, 0, stream>>>(Whh, wimg);
  k_prep_ge<<<dim3(9, 8), 256, 0, stream>>>(emb, Wih, bih, ge);

  hipFuncSetAttribute(reinterpret_cast<const void*>(k_gru),
                      hipFuncAttributeMaxDynamicSharedMemorySize, LDS_BYTES);
  k_gru<<<NGRP * NU, 128, LDS_BYTES, stream>>>(x, ge, bhh, wimg, h16, h32, flags);

  k_fc<<<dim3(3, 8), 256, 0, stream>>>(h32, fcW, fcb, out);
}